// Round 1
// baseline (21134.895 us; speedup 1.0000x reference)
//
#include <hip/hip_runtime.h>

// ---------------------------------------------------------------------------
// TLSTM (time-aware LSTM): B=256, S=512, D=H=512, FC=64, O=2
//
// Round-0 design:
//   * persistent cooperative kernel, 256 WGs = 16 row-groups x 16 col-groups
//   * gate/decomp weights pre-packed to f16 B^T fragments, REGISTER-resident
//     across all 512 timesteps (zero per-step weight traffic)
//   * per step: stage x_t (fp32->f16) + h_prev + c_prev (f16) to LDS,
//     v_mfma_f32_16x16x32_f16 with K split over the 4 waves, partial sums
//     reduced via LDS atomicAdd into bias-initialized tiles, fused
//     elementwise cell update (fp32 state), f16 h/c double-buffer publish,
//     device-scope tree barrier (8 groups x 32 WGs, monotonic epoch)
//   * fp32 head (h_last @ Wo -> relu -> @ W_softmax) as a tiny second kernel
// ---------------------------------------------------------------------------

typedef _Float16 f16;
typedef _Float16 f16x8 __attribute__((ext_vector_type(8)));
typedef float f32x4 __attribute__((ext_vector_type(4)));

#define B_ 256
#define S_ 512
#define D_ 512
#define H_ 512

// workspace layout (bytes)
#define WS_WTG  0u          // f16 [2048][1024] gate weights^T (Wg|Ug stacked on K)
#define WS_WTD  4194304u    // f16 [512][512]   decomp weights^T
#define WS_H16  4718592u    // f16 [2][256][512] h double buffer
#define WS_C16  5242880u    // f16 [2][256][512] c double buffer
#define WS_CF32 5767168u    // f32 [256][512]   c state (owner-local)
#define WS_HF32 6291456u    // f32 [256][512]   h state (for head)
#define WS_BAR  6815744u    // int barrier block: cnt[8*32], gcnt@256, epoch@288
#define WS_END  6819840u

__device__ __forceinline__ float fast_sigmoid(float x) {
  return 1.0f / (1.0f + __expf(-x));
}
__device__ __forceinline__ float fast_tanh(float x) {
  x = fminf(15.0f, fmaxf(-15.0f, x));
  float e = __expf(2.0f * x);
  return (e - 1.0f) / (e + 1.0f);
}

// ---------------------------------------------------------------------------
// Pack weights: WT_g[n][k] (n = gate*512+col, k<512 -> W[k][col], k>=512 ->
// U[k-512][col]), WT_d[n][k] = W_decomp[k][n].  Writes coalesced; scattered
// fp32 reads are absorbed by L2 (9.4 MB working set).
// ---------------------------------------------------------------------------
__global__ void pack_weights(const float* __restrict__ Wi, const float* __restrict__ Ui,
                             const float* __restrict__ Wf, const float* __restrict__ Uf,
                             const float* __restrict__ Wog, const float* __restrict__ Uog,
                             const float* __restrict__ Wc, const float* __restrict__ Uc,
                             const float* __restrict__ Wd,
                             f16* __restrict__ wtg, f16* __restrict__ wtd)
{
  const int idx = blockIdx.x * 256 + threadIdx.x;
  if (idx < 2048 * 1024) {
    const int n = idx >> 10, k = idx & 1023;
    const int g = n >> 9, j = n & 511;
    const float* W[8] = {Wi, Ui, Wf, Uf, Wog, Uog, Wc, Uc};
    const float* src = W[(g << 1) + (k >> 9)];
    wtg[idx] = (f16)src[(size_t)(k & 511) * 512 + j];
  } else {
    const int i2 = idx - 2048 * 1024;   // grid sized exactly, i2 < 512*512
    const int n = i2 >> 9, k = i2 & 511;
    wtd[i2] = (f16)Wd[(size_t)k * 512 + n];
  }
}

// ---------------------------------------------------------------------------
// Main persistent kernel.
// ---------------------------------------------------------------------------
__global__ void __launch_bounds__(256, 1)
tlstm_main(const float* __restrict__ x, const float* __restrict__ tim,
           const float* __restrict__ bi, const float* __restrict__ bf,
           const float* __restrict__ bog, const float* __restrict__ bc,
           const float* __restrict__ bdec,
           const f16* __restrict__ wtg, const f16* __restrict__ wtd,
           f16* __restrict__ h16, f16* __restrict__ c16,
           float* __restrict__ cf32, float* __restrict__ hf32,
           int* __restrict__ bar)
{
  // LDS: +8 f16 row pad keeps ds_read_b128 16B-aligned & bank-spread
  __shared__ __align__(16) f16 Ag[16][1032];   // [row][k]: k<512 x_t, k>=512 h_prev
  __shared__ __align__(16) f16 Ad[16][520];    // [row][k]: c_prev
  __shared__ float accS[10][272];              // 10 16x16 tiles, row stride 17
  __shared__ float biasS[10][16];

  const int tid  = threadIdx.x;
  const int lane = tid & 63;
  const int wv   = tid >> 6;     // wave 0..3
  const int l15  = lane & 15;
  const int lq   = lane >> 4;
  const int bid  = blockIdx.x;
  const int rowg = bid & 15;     // row-group -> XCD rowg%8 (with %8 round-robin)
  const int colg = bid >> 4;
  const int row0 = rowg << 4;    // 16 batch rows
  const int jc0  = colg << 5;    // 32 h-columns

  // ---- persistent weight B-fragments in registers ----
  // unit u = gate*2+ct for u<8 (gates i,f,o,c~), u=8+ct for decomp
  f16x8 Bg[4][2][8];
  #pragma unroll
  for (int g = 0; g < 4; ++g) {
    #pragma unroll
    for (int ct = 0; ct < 2; ++ct) {
      const int n = (g << 9) + jc0 + (ct << 4) + l15;
      #pragma unroll
      for (int t = 0; t < 8; ++t) {
        const int k = ((wv << 3) + t) * 32 + (lq << 3);
        Bg[g][ct][t] = *(const f16x8*)(wtg + (size_t)n * 1024 + k);
      }
    }
  }
  f16x8 Bd[2][4];
  #pragma unroll
  for (int ct = 0; ct < 2; ++ct) {
    const int n = jc0 + (ct << 4) + l15;
    #pragma unroll
    for (int t = 0; t < 4; ++t) {
      const int k = ((wv << 2) + t) * 32 + (lq << 3);
      Bd[ct][t] = *(const f16x8*)(wtd + (size_t)n * 512 + k);
    }
  }

  // ---- biases -> LDS once ----
  if (tid < 160) {
    const int u = tid >> 4, c = tid & 15;
    const float* bp = (u < 2) ? bi : (u < 4) ? bf : (u < 6) ? bog : (u < 8) ? bc : bdec;
    biasS[u][c] = bp[jc0 + ((u & 1) << 4) + c];
  }
  __syncthreads();

  const f16* AgF = &Ag[0][0];
  const f16* AdF = &Ad[0][0];
  const int a_base  = l15 * 1032 + (lq << 3);
  const int ad_base = l15 * 520 + (lq << 3);

  for (int s = 0; s < S_; ++s) {
    const int cur = s & 1, nxt = cur ^ 1;
    const f16* hcur = h16 + (size_t)cur * (B_ * H_);
    const f16* ccur = c16 + (size_t)cur * (B_ * H_);

    // bias-init accumulator tiles
    {
      const int r = tid >> 4, c = tid & 15;
      const int li = r * 17 + c;
      #pragma unroll
      for (int u = 0; u < 10; ++u) accS[u][li] = biasS[u][c];
    }

    // stage x_t (cvt fp32->f16), h_prev, c_prev; 4 rows per wave
    #pragma unroll
    for (int rr = 0; rr < 4; ++rr) {
      const int r = (wv << 2) + rr;
      const int gb = row0 + r;
      const float4* xr = (const float4*)(x + ((size_t)gb * S_ + s) * D_);
      float4 v0 = xr[lane * 2];
      float4 v1 = xr[lane * 2 + 1];
      f16x8 xv;
      xv[0] = (f16)v0.x; xv[1] = (f16)v0.y; xv[2] = (f16)v0.z; xv[3] = (f16)v0.w;
      xv[4] = (f16)v1.x; xv[5] = (f16)v1.y; xv[6] = (f16)v1.z; xv[7] = (f16)v1.w;
      *(f16x8*)&Ag[r][lane << 3] = xv;
      *(uint4*)&Ag[r][512 + (lane << 3)] = *(const uint4*)(hcur + (size_t)gb * H_ + (lane << 3));
      *(uint4*)&Ad[r][lane << 3]         = *(const uint4*)(ccur + (size_t)gb * H_ + (lane << 3));
    }
    __syncthreads();

    // MFMA: K split across 4 waves (wave w: gate ksteps 8w..8w+8, dec 4w..4w+4)
    f32x4 acc[10];
    #pragma unroll
    for (int u = 0; u < 10; ++u) acc[u] = (f32x4){0.f, 0.f, 0.f, 0.f};
    #pragma unroll
    for (int t = 0; t < 8; ++t) {
      f16x8 a = *(const f16x8*)(AgF + a_base + ((wv << 3) + t) * 32);
      #pragma unroll
      for (int g = 0; g < 4; ++g) {
        #pragma unroll
        for (int ct = 0; ct < 2; ++ct)
          acc[(g << 1) + ct] =
              __builtin_amdgcn_mfma_f32_16x16x32_f16(a, Bg[g][ct][t], acc[(g << 1) + ct], 0, 0, 0);
      }
    }
    #pragma unroll
    for (int t = 0; t < 4; ++t) {
      f16x8 a = *(const f16x8*)(AdF + ad_base + ((wv << 2) + t) * 32);
      acc[8] = __builtin_amdgcn_mfma_f32_16x16x32_f16(a, Bd[0][t], acc[8], 0, 0, 0);
      acc[9] = __builtin_amdgcn_mfma_f32_16x16x32_f16(a, Bd[1][t], acc[9], 0, 0, 0);
    }
    // reduce partials (ds_add_f32); C-frag: row=(lane>>4)*4+i, col=lane&15
    #pragma unroll
    for (int u = 0; u < 10; ++u) {
      #pragma unroll
      for (int i = 0; i < 4; ++i)
        atomicAdd(&accS[u][((lq << 2) + i) * 17 + l15], acc[u][i]);
    }
    __syncthreads();

    // elementwise cell update: 2 outputs (row,col) per thread
    #pragma unroll
    for (int e2 = 0; e2 < 2; ++e2) {
      const int e  = tid + (e2 << 8);
      const int r  = e >> 5, cc = e & 31;
      const int ct = cc >> 4, cl = cc & 15;
      const int li = r * 17 + cl;
      const float pi = accS[0 + ct][li];
      const float pf = accS[2 + ct][li];
      const float po = accS[4 + ct][li];
      const float pc = accS[6 + ct][li];
      const float ps = accS[8 + ct][li];
      const int gb = row0 + r;
      const int jg = jc0 + cc;
      const float tv   = tim[(size_t)gb * S_ + s];
      const float T    = 1.0f / __logf(tv + 2.7183f);   // exact ref constant
      const float cst  = fast_tanh(ps);
      const float cprev = cf32[(size_t)gb * H_ + jg];
      const float chat = cprev - cst + T * cst;
      const float ig = fast_sigmoid(pi);
      const float fg = fast_sigmoid(pf);
      const float og = fast_sigmoid(po);
      const float cnv  = fast_tanh(pc);
      const float cnew = fg * chat + ig * cnv;
      const float hnew = og * fast_tanh(cnew);
      cf32[(size_t)gb * H_ + jg] = cnew;
      hf32[(size_t)gb * H_ + jg] = hnew;
      h16[(size_t)nxt * (B_ * H_) + (size_t)gb * H_ + jg] = (f16)hnew;
      c16[(size_t)nxt * (B_ * H_) + (size_t)gb * H_ + jg] = (f16)cnew;
    }
    __syncthreads();

    // ---- device-scope tree barrier (monotonic counters, no reset races) ----
    if (tid == 0) {
      __threadfence();  // release: drain + L2 writeback for cross-XCD readers
      const int g8 = bid & 7;
      int c = __hip_atomic_fetch_add(&bar[g8 * 32], 1, __ATOMIC_RELAXED,
                                     __HIP_MEMORY_SCOPE_AGENT) + 1;
      if (c == 32 * (s + 1)) {
        int gc = __hip_atomic_fetch_add(&bar[256], 1, __ATOMIC_RELAXED,
                                        __HIP_MEMORY_SCOPE_AGENT) + 1;
        if (gc == 8 * (s + 1))
          __hip_atomic_store(&bar[288], s + 1, __ATOMIC_RELEASE,
                             __HIP_MEMORY_SCOPE_AGENT);
      }
      while (__hip_atomic_load(&bar[288], __ATOMIC_RELAXED,
                               __HIP_MEMORY_SCOPE_AGENT) < s + 1)
        __builtin_amdgcn_s_sleep(2);
    }
    __syncthreads();
    __threadfence();  // acquire: invalidate stale cached h/c before next stage
  }
}

// ---------------------------------------------------------------------------
// Head: out = relu(h_last @ Wo + bo) @ W_softmax + b_softmax   (fp32 exact)
// ---------------------------------------------------------------------------
__global__ void head_kernel(const float* __restrict__ hf32,
                            const float* __restrict__ Wo, const float* __restrict__ bo,
                            const float* __restrict__ Wsm, const float* __restrict__ bsm,
                            float* __restrict__ out)
{
  __shared__ float fcS[4][64];
  const int tid = threadIdx.x;
  const int r = tid >> 6, j = tid & 63;
  const int b = blockIdx.x * 4 + r;
  const float* h = hf32 + (size_t)b * 512;
  float acc = 0.f;
  #pragma unroll 8
  for (int k = 0; k < 512; ++k) acc += h[k] * Wo[k * 64 + j];
  fcS[r][j] = fmaxf(acc + bo[j], 0.f);
  __syncthreads();
  if (tid < 8) {
    const int rr = tid >> 1, o = tid & 1;
    float s = bsm[o];
    #pragma unroll 8
    for (int jj = 0; jj < 64; ++jj) s += fcS[rr][jj] * Wsm[jj * 2 + o];
    out[(size_t)(blockIdx.x * 4 + rr) * 2 + o] = s;
  }
}

// ---------------------------------------------------------------------------
extern "C" void kernel_launch(void* const* d_in, const int* in_sizes, int n_in,
                              void* d_out, int out_size, void* d_ws, size_t ws_size,
                              hipStream_t stream)
{
  if (ws_size < (size_t)WS_END) return;  // need ~6.6 MB scratch

  const float* x    = (const float*)d_in[0];
  const float* tim  = (const float*)d_in[1];
  const float* Wi   = (const float*)d_in[2];
  const float* Ui   = (const float*)d_in[3];
  const float* bi   = (const float*)d_in[4];
  const float* Wf   = (const float*)d_in[5];
  const float* Uf   = (const float*)d_in[6];
  const float* bf   = (const float*)d_in[7];
  const float* Wog  = (const float*)d_in[8];
  const float* Uog  = (const float*)d_in[9];
  const float* bog  = (const float*)d_in[10];
  const float* Wc   = (const float*)d_in[11];
  const float* Uc   = (const float*)d_in[12];
  const float* bc   = (const float*)d_in[13];
  const float* Wd   = (const float*)d_in[14];
  const float* bd   = (const float*)d_in[15];
  const float* Wo   = (const float*)d_in[16];
  const float* bo   = (const float*)d_in[17];
  const float* Wsm  = (const float*)d_in[18];
  const float* bsm  = (const float*)d_in[19];

  char* ws   = (char*)d_ws;
  f16*  wtg  = (f16*)(ws + WS_WTG);
  f16*  wtd  = (f16*)(ws + WS_WTD);
  f16*  h16  = (f16*)(ws + WS_H16);
  f16*  c16  = (f16*)(ws + WS_C16);
  float* cf32 = (float*)(ws + WS_CF32);
  float* hf32 = (float*)(ws + WS_HF32);
  int*  bar  = (int*)(ws + WS_BAR);

  // zero h/c buffers + states + barrier (ws is poisoned 0xAA before each call)
  (void)hipMemsetAsync(ws + WS_H16, 0, WS_END - WS_H16, stream);

  pack_weights<<<9216, 256, 0, stream>>>(Wi, Ui, Wf, Uf, Wog, Uog, Wc, Uc, Wd, wtg, wtd);
  tlstm_main<<<256, 256, 0, stream>>>(x, tim, bi, bf, bog, bc, bd, wtg, wtd,
                                      h16, c16, cf32, hf32, bar);
  head_kernel<<<64, 256, 0, stream>>>(hf32, Wo, bo, Wsm, bsm, (float*)d_out);
}

// Round 2
// 10317.067 us; speedup vs baseline: 2.0485x; 2.0485x over previous
//
#include <hip/hip_runtime.h>

// ---------------------------------------------------------------------------
// TLSTM (time-aware LSTM): B=256, S=512, D=H=512, FC=64, O=2
//
// Round-1 design (round-0 + fence elimination):
//   * persistent kernel, 256 WGs = 16 row-groups x 16 col-groups
//   * gate/decomp weights pre-packed f16 B^T fragments, register-resident
//   * per step: stage x_t(cvt) + h_prev + c_prev to LDS, 16x16x32 f16 MFMA
//     with K split over 4 waves, LDS atomicAdd reduction, fused cell update
//   * NO __threadfence (was: full L2 wbl2+inv per wave per step = ~37us/step).
//     Cross-XCD h/c exchange now uses agent-scope RELAXED atomic dword
//     load/store (global_load/store sc1 -> coherent at Infinity Cache).
//   * barrier is per-row-group (16 WGs, one monotonic counter), not global
//   * c-state lives in registers (owner-stationary); hf32 written at s=511
// ---------------------------------------------------------------------------

typedef _Float16 f16;
typedef _Float16 f16x8 __attribute__((ext_vector_type(8)));
typedef float f32x4 __attribute__((ext_vector_type(4)));

#define B_ 256
#define S_ 512
#define D_ 512
#define H_ 512

// workspace layout (bytes)
#define WS_WTG  0u          // f16 [2048][1024] gate weights^T (W|U stacked on K)
#define WS_WTD  4194304u    // f16 [512][512]   decomp weights^T
#define WS_H16  4718592u    // f16 [2][256][512] h double buffer
#define WS_C16  5242880u    // f16 [2][256][512] c double buffer
#define WS_HF32 5767168u    // f32 [256][512]   h last (for head)
#define WS_BAR  6291456u    // int barrier: bar[rowg*64], 16 counters
#define WS_END  6295552u

__device__ __forceinline__ float fast_sigmoid(float x) {
  return 1.0f / (1.0f + __expf(-x));
}
__device__ __forceinline__ float fast_tanh(float x) {
  x = fminf(15.0f, fmaxf(-15.0f, x));
  float e = __expf(2.0f * x);
  return (e - 1.0f) / (e + 1.0f);
}
__device__ __forceinline__ unsigned pack_f16x2(float a, float b) {
  union { f16 h[2]; unsigned u; } p;
  p.h[0] = (f16)a; p.h[1] = (f16)b;
  return p.u;
}
// agent-scope (device-coherent, Infinity-Cache-served) dword ops
__device__ __forceinline__ unsigned ld_agent(const unsigned* p) {
  return __hip_atomic_load(p, __ATOMIC_RELAXED, __HIP_MEMORY_SCOPE_AGENT);
}
__device__ __forceinline__ void st_agent(unsigned* p, unsigned v) {
  __hip_atomic_store(p, v, __ATOMIC_RELAXED, __HIP_MEMORY_SCOPE_AGENT);
}

// ---------------------------------------------------------------------------
// Pack weights: WT_g[n][k] (n = gate*512+col; k<512 -> W[k][col], k>=512 ->
// U[k-512][col]), WT_d[n][k] = W_decomp[k][n].
// ---------------------------------------------------------------------------
__global__ void pack_weights(const float* __restrict__ Wi, const float* __restrict__ Ui,
                             const float* __restrict__ Wf, const float* __restrict__ Uf,
                             const float* __restrict__ Wog, const float* __restrict__ Uog,
                             const float* __restrict__ Wc, const float* __restrict__ Uc,
                             const float* __restrict__ Wd,
                             f16* __restrict__ wtg, f16* __restrict__ wtd)
{
  const int idx = blockIdx.x * 256 + threadIdx.x;
  if (idx < 2048 * 1024) {
    const int n = idx >> 10, k = idx & 1023;
    const int g = n >> 9, j = n & 511;
    const float* W[8] = {Wi, Ui, Wf, Uf, Wog, Uog, Wc, Uc};
    const float* src = W[(g << 1) + (k >> 9)];
    wtg[idx] = (f16)src[(size_t)(k & 511) * 512 + j];
  } else {
    const int i2 = idx - 2048 * 1024;
    const int n = i2 >> 9, k = i2 & 511;
    wtd[i2] = (f16)Wd[(size_t)k * 512 + n];
  }
}

// ---------------------------------------------------------------------------
// Main persistent kernel.
// ---------------------------------------------------------------------------
__global__ void __launch_bounds__(256, 1)
tlstm_main(const float* __restrict__ x, const float* __restrict__ tim,
           const float* __restrict__ bi, const float* __restrict__ bf,
           const float* __restrict__ bog, const float* __restrict__ bc,
           const float* __restrict__ bdec,
           const f16* __restrict__ wtg, const f16* __restrict__ wtd,
           f16* __restrict__ h16, f16* __restrict__ c16,
           float* __restrict__ hf32, int* __restrict__ bar)
{
  __shared__ __align__(16) f16 Ag[16][1032];   // [row][k]: k<512 x_t, k>=512 h_prev
  __shared__ __align__(16) f16 Ad[16][520];    // [row][k]: c_prev
  __shared__ float accS[10][272];              // 10 16x16 tiles, row stride 17
  __shared__ float biasS[10][16];

  const int tid  = threadIdx.x;
  const int lane = tid & 63;
  const int wv   = tid >> 6;     // wave 0..3
  const int l15  = lane & 15;
  const int lq   = lane >> 4;
  const int bid  = blockIdx.x;
  const int rowg = bid & 15;
  const int colg = bid >> 4;
  const int row0 = rowg << 4;    // 16 batch rows
  const int jc0  = colg << 5;    // 32 h-columns

  // ---- persistent weight B-fragments in registers ----
  f16x8 Bg[4][2][8];
  #pragma unroll
  for (int g = 0; g < 4; ++g)
    #pragma unroll
    for (int ct = 0; ct < 2; ++ct) {
      const int n = (g << 9) + jc0 + (ct << 4) + l15;
      #pragma unroll
      for (int t = 0; t < 8; ++t) {
        const int k = ((wv << 3) + t) * 32 + (lq << 3);
        Bg[g][ct][t] = *(const f16x8*)(wtg + (size_t)n * 1024 + k);
      }
    }
  f16x8 Bd[2][4];
  #pragma unroll
  for (int ct = 0; ct < 2; ++ct) {
    const int n = jc0 + (ct << 4) + l15;
    #pragma unroll
    for (int t = 0; t < 4; ++t) {
      const int k = ((wv << 2) + t) * 32 + (lq << 3);
      Bd[ct][t] = *(const f16x8*)(wtd + (size_t)n * 512 + k);
    }
  }

  // ---- biases -> LDS once ----
  if (tid < 160) {
    const int u = tid >> 4, c = tid & 15;
    const float* bp = (u < 2) ? bi : (u < 4) ? bf : (u < 6) ? bog : (u < 8) ? bc : bdec;
    biasS[u][c] = bp[jc0 + ((u & 1) << 4) + c];
  }
  __syncthreads();

  const f16* AgF = &Ag[0][0];
  const f16* AdF = &Ad[0][0];
  const int a_base  = l15 * 1032 + (lq << 3);
  const int ad_base = l15 * 520 + (lq << 3);

  // owner-stationary c state: thread owns (row er, cols 2*eq, 2*eq+1)
  const int er   = tid >> 4;
  const int eq   = tid & 15;
  const int gb_e = row0 + er;
  float c_reg[2] = {0.f, 0.f};

  int* const my_bar = &bar[rowg * 64];

  for (int s = 0; s < S_; ++s) {
    const int cur = s & 1, nxt = cur ^ 1;
    const f16* hcur = h16 + (size_t)cur * (B_ * H_);
    const f16* ccur = c16 + (size_t)cur * (B_ * H_);

    // bias-init accumulator tiles
    {
      const int r = tid >> 4, c = tid & 15;
      const int li = r * 17 + c;
      #pragma unroll
      for (int u = 0; u < 10; ++u) accS[u][li] = biasS[u][c];
    }

    // stage x_t (fp32->f16), h_prev, c_prev (agent-coherent); 4 rows/wave
    #pragma unroll
    for (int rr = 0; rr < 4; ++rr) {
      const int r = (wv << 2) + rr;
      const int gb = row0 + r;
      const float4* xr = (const float4*)(x + ((size_t)gb * S_ + s) * D_);
      float4 v0 = xr[lane * 2];
      float4 v1 = xr[lane * 2 + 1];
      f16x8 xv;
      xv[0] = (f16)v0.x; xv[1] = (f16)v0.y; xv[2] = (f16)v0.z; xv[3] = (f16)v0.w;
      xv[4] = (f16)v1.x; xv[5] = (f16)v1.y; xv[6] = (f16)v1.z; xv[7] = (f16)v1.w;
      *(f16x8*)&Ag[r][lane << 3] = xv;
      const unsigned* hp = (const unsigned*)(hcur + (size_t)gb * H_) + (lane << 2);
      const unsigned* cp = (const unsigned*)(ccur + (size_t)gb * H_) + (lane << 2);
      uint4 hv4, cv4;
      hv4.x = ld_agent(hp + 0); hv4.y = ld_agent(hp + 1);
      hv4.z = ld_agent(hp + 2); hv4.w = ld_agent(hp + 3);
      cv4.x = ld_agent(cp + 0); cv4.y = ld_agent(cp + 1);
      cv4.z = ld_agent(cp + 2); cv4.w = ld_agent(cp + 3);
      *(uint4*)&Ag[r][512 + (lane << 3)] = hv4;
      *(uint4*)&Ad[r][lane << 3]         = cv4;
    }
    __syncthreads();

    // MFMA: K split across 4 waves
    f32x4 acc[10];
    #pragma unroll
    for (int u = 0; u < 10; ++u) acc[u] = (f32x4){0.f, 0.f, 0.f, 0.f};
    #pragma unroll
    for (int t = 0; t < 8; ++t) {
      f16x8 a = *(const f16x8*)(AgF + a_base + ((wv << 3) + t) * 32);
      #pragma unroll
      for (int g = 0; g < 4; ++g)
        #pragma unroll
        for (int ct = 0; ct < 2; ++ct)
          acc[(g << 1) + ct] =
              __builtin_amdgcn_mfma_f32_16x16x32_f16(a, Bg[g][ct][t], acc[(g << 1) + ct], 0, 0, 0);
    }
    #pragma unroll
    for (int t = 0; t < 4; ++t) {
      f16x8 a = *(const f16x8*)(AdF + ad_base + ((wv << 2) + t) * 32);
      acc[8] = __builtin_amdgcn_mfma_f32_16x16x32_f16(a, Bd[0][t], acc[8], 0, 0, 0);
      acc[9] = __builtin_amdgcn_mfma_f32_16x16x32_f16(a, Bd[1][t], acc[9], 0, 0, 0);
    }
    // reduce wave partials; C-frag: row=(lane>>4)*4+i, col=lane&15
    #pragma unroll
    for (int u = 0; u < 10; ++u)
      #pragma unroll
      for (int i = 0; i < 4; ++i)
        atomicAdd(&accS[u][((lq << 2) + i) * 17 + l15], acc[u][i]);
    __syncthreads();

    // elementwise cell update: thread owns (er, 2*eq) and (er, 2*eq+1)
    {
      const float tv = tim[(size_t)gb_e * S_ + s];
      const float T  = 1.0f / __logf(tv + 2.7183f);   // exact ref constant
      float hv[2];
      #pragma unroll
      for (int j = 0; j < 2; ++j) {
        const int cc = (eq << 1) + j;
        const int ct = cc >> 4, cl = cc & 15;
        const int li = er * 17 + cl;
        const float pi = accS[0 + ct][li];
        const float pf = accS[2 + ct][li];
        const float po = accS[4 + ct][li];
        const float pc = accS[6 + ct][li];
        const float ps = accS[8 + ct][li];
        const float cst  = fast_tanh(ps);
        const float chat = c_reg[j] - cst + T * cst;
        const float cnew = fast_sigmoid(pf) * chat + fast_sigmoid(pi) * fast_tanh(pc);
        const float hnew = fast_sigmoid(po) * fast_tanh(cnew);
        c_reg[j] = cnew;
        hv[j] = hnew;
      }
      const size_t off = (size_t)gb_e * H_ + jc0 + (eq << 1);
      st_agent((unsigned*)(h16 + (size_t)nxt * (B_ * H_) + off), pack_f16x2(hv[0], hv[1]));
      st_agent((unsigned*)(c16 + (size_t)nxt * (B_ * H_) + off), pack_f16x2(c_reg[0], c_reg[1]));
      if (s == S_ - 1) {
        *(float2*)(hf32 + off) = make_float2(hv[0], hv[1]);
      }
    }
    __syncthreads();   // drains all waves' vmcnt -> sc1 stores at coherence point

    // ---- per-row-group barrier: 16 WGs, one monotonic counter ----
    if (s != S_ - 1) {
      if (tid == 0) {
        asm volatile("s_waitcnt vmcnt(0)" ::: "memory");
        __hip_atomic_fetch_add(my_bar, 1, __ATOMIC_RELAXED, __HIP_MEMORY_SCOPE_AGENT);
        while (__hip_atomic_load(my_bar, __ATOMIC_RELAXED, __HIP_MEMORY_SCOPE_AGENT)
               < 16 * (s + 1))
          __builtin_amdgcn_s_sleep(1);
      }
      __syncthreads();
    }
  }
}

// ---------------------------------------------------------------------------
// Head: out = relu(h_last @ Wo + bo) @ W_softmax + b_softmax   (fp32 exact)
// ---------------------------------------------------------------------------
__global__ void head_kernel(const float* __restrict__ hf32,
                            const float* __restrict__ Wo, const float* __restrict__ bo,
                            const float* __restrict__ Wsm, const float* __restrict__ bsm,
                            float* __restrict__ out)
{
  __shared__ float fcS[4][64];
  const int tid = threadIdx.x;
  const int r = tid >> 6, j = tid & 63;
  const int b = blockIdx.x * 4 + r;
  const float* h = hf32 + (size_t)b * 512;
  float acc = 0.f;
  #pragma unroll 8
  for (int k = 0; k < 512; ++k) acc += h[k] * Wo[k * 64 + j];
  fcS[r][j] = fmaxf(acc + bo[j], 0.f);
  __syncthreads();
  if (tid < 8) {
    const int rr = tid >> 1, o = tid & 1;
    float s = bsm[o];
    #pragma unroll 8
    for (int jj = 0; jj < 64; ++jj) s += fcS[rr][jj] * Wsm[jj * 2 + o];
    out[(size_t)(blockIdx.x * 4 + rr) * 2 + o] = s;
  }
}

// ---------------------------------------------------------------------------
extern "C" void kernel_launch(void* const* d_in, const int* in_sizes, int n_in,
                              void* d_out, int out_size, void* d_ws, size_t ws_size,
                              hipStream_t stream)
{
  if (ws_size < (size_t)WS_END) return;

  const float* x    = (const float*)d_in[0];
  const float* tim  = (const float*)d_in[1];
  const float* Wi   = (const float*)d_in[2];
  const float* Ui   = (const float*)d_in[3];
  const float* bi   = (const float*)d_in[4];
  const float* Wf   = (const float*)d_in[5];
  const float* Uf   = (const float*)d_in[6];
  const float* bf   = (const float*)d_in[7];
  const float* Wog  = (const float*)d_in[8];
  const float* Uog  = (const float*)d_in[9];
  const float* bog  = (const float*)d_in[10];
  const float* Wc   = (const float*)d_in[11];
  const float* Uc   = (const float*)d_in[12];
  const float* bc   = (const float*)d_in[13];
  const float* Wd   = (const float*)d_in[14];
  const float* bd   = (const float*)d_in[15];
  const float* Wo   = (const float*)d_in[16];
  const float* bo   = (const float*)d_in[17];
  const float* Wsm  = (const float*)d_in[18];
  const float* bsm  = (const float*)d_in[19];

  char* ws    = (char*)d_ws;
  f16*  wtg   = (f16*)(ws + WS_WTG);
  f16*  wtd   = (f16*)(ws + WS_WTD);
  f16*  h16   = (f16*)(ws + WS_H16);
  f16*  c16   = (f16*)(ws + WS_C16);
  float* hf32 = (float*)(ws + WS_HF32);
  int*  bar   = (int*)(ws + WS_BAR);

  // zero h/c buffers + hf32 + barrier (ws is poisoned 0xAA before each call)
  (void)hipMemsetAsync(ws + WS_H16, 0, WS_END - WS_H16, stream);

  pack_weights<<<9216, 256, 0, stream>>>(Wi, Ui, Wf, Uf, Wog, Uog, Wc, Uc, Wd, wtg, wtd);
  tlstm_main<<<256, 256, 0, stream>>>(x, tim, bi, bf, bog, bc, bd, wtg, wtd,
                                      h16, c16, hf32, bar);
  head_kernel<<<64, 256, 0, stream>>>(hf32, Wo, bo, Wsm, bsm, (float*)d_out);
}

// Round 3
// 9325.096 us; speedup vs baseline: 2.2665x; 1.1064x over previous
//
#include <hip/hip_runtime.h>

// ---------------------------------------------------------------------------
// TLSTM (time-aware LSTM): B=256, S=512, D=H=512, FC=64, O=2
//
// Round-2 design (round-1 + staged-load fix):
//   * persistent kernel, 256 WGs = 16 row-groups x 16 col-groups
//   * gate/decomp weights pre-packed f16 B^T fragments, register-resident
//   * h/c exchange: plain global_load_dwordx4 ... sc1 (device-scope, served
//     by Infinity Cache) batched in ONE inline-asm block with ONE
//     s_waitcnt vmcnt(0) -> 1 round trip instead of ~8-24 serialized atomic
//     dword round trips (the round-1 19.6us/step culprit)
//   * barrier arrive at top of iteration; x load/cvt + bias init overlap the
//     barrier poll window
//   * barrier is per-row-group (16 WGs, one monotonic counter)
//   * c-state in registers (owner-stationary); hf32 written at s=511
// ---------------------------------------------------------------------------

typedef _Float16 f16;
typedef _Float16 f16x8 __attribute__((ext_vector_type(8)));
typedef float f32x4 __attribute__((ext_vector_type(4)));
typedef unsigned u32x4 __attribute__((ext_vector_type(4)));

#define B_ 256
#define S_ 512
#define D_ 512
#define H_ 512

// workspace layout (bytes)
#define WS_WTG  0u          // f16 [2048][1024] gate weights^T (W|U stacked on K)
#define WS_WTD  4194304u    // f16 [512][512]   decomp weights^T
#define WS_H16  4718592u    // f16 [2][256][512] h double buffer
#define WS_C16  5242880u    // f16 [2][256][512] c double buffer
#define WS_HF32 5767168u    // f32 [256][512]   h last (for head)
#define WS_BAR  6291456u    // int barrier: bar[rowg*64], 16 counters
#define WS_END  6295552u

__device__ __forceinline__ float fast_sigmoid(float x) {
  return 1.0f / (1.0f + __expf(-x));
}
__device__ __forceinline__ float fast_tanh(float x) {
  x = fminf(15.0f, fmaxf(-15.0f, x));
  float e = __expf(2.0f * x);
  return (e - 1.0f) / (e + 1.0f);
}
__device__ __forceinline__ unsigned pack_f16x2(float a, float b) {
  union { f16 h[2]; unsigned u; } p;
  p.h[0] = (f16)a; p.h[1] = (f16)b;
  return p.u;
}
// agent-scope store (device-coherent at IC); no result wait on stores
__device__ __forceinline__ void st_agent(unsigned* p, unsigned v) {
  __hip_atomic_store(p, v, __ATOMIC_RELAXED, __HIP_MEMORY_SCOPE_AGENT);
}

// ---------------------------------------------------------------------------
// Pack weights: WT_g[n][k] (n = gate*512+col; k<512 -> W[k][col], k>=512 ->
// U[k-512][col]), WT_d[n][k] = W_decomp[k][n].
// ---------------------------------------------------------------------------
__global__ void pack_weights(const float* __restrict__ Wi, const float* __restrict__ Ui,
                             const float* __restrict__ Wf, const float* __restrict__ Uf,
                             const float* __restrict__ Wog, const float* __restrict__ Uog,
                             const float* __restrict__ Wc, const float* __restrict__ Uc,
                             const float* __restrict__ Wd,
                             f16* __restrict__ wtg, f16* __restrict__ wtd)
{
  const int idx = blockIdx.x * 256 + threadIdx.x;
  if (idx < 2048 * 1024) {
    const int n = idx >> 10, k = idx & 1023;
    const int g = n >> 9, j = n & 511;
    const float* W[8] = {Wi, Ui, Wf, Uf, Wog, Uog, Wc, Uc};
    const float* src = W[(g << 1) + (k >> 9)];
    wtg[idx] = (f16)src[(size_t)(k & 511) * 512 + j];
  } else {
    const int i2 = idx - 2048 * 1024;
    const int n = i2 >> 9, k = i2 & 511;
    wtd[i2] = (f16)Wd[(size_t)k * 512 + n];
  }
}

// ---------------------------------------------------------------------------
// Main persistent kernel.
// ---------------------------------------------------------------------------
__global__ void __launch_bounds__(256, 1)
tlstm_main(const float* __restrict__ x, const float* __restrict__ tim,
           const float* __restrict__ bi, const float* __restrict__ bf,
           const float* __restrict__ bog, const float* __restrict__ bc,
           const float* __restrict__ bdec,
           const f16* __restrict__ wtg, const f16* __restrict__ wtd,
           f16* __restrict__ h16, f16* __restrict__ c16,
           float* __restrict__ hf32, int* __restrict__ bar)
{
  __shared__ __align__(16) f16 Ag[16][1032];   // [row][k]: k<512 x_t, k>=512 h_prev
  __shared__ __align__(16) f16 Ad[16][520];    // [row][k]: c_prev
  __shared__ float accS[10][272];              // 10 16x16 tiles, row stride 17
  __shared__ float biasS[10][16];

  const int tid  = threadIdx.x;
  const int lane = tid & 63;
  const int wv   = tid >> 6;     // wave 0..3
  const int l15  = lane & 15;
  const int lq   = lane >> 4;
  const int bid  = blockIdx.x;
  const int rowg = bid & 15;
  const int colg = bid >> 4;
  const int row0 = rowg << 4;    // 16 batch rows
  const int jc0  = colg << 5;    // 32 h-columns

  // ---- persistent weight B-fragments in registers ----
  f16x8 Bg[4][2][8];
  #pragma unroll
  for (int g = 0; g < 4; ++g)
    #pragma unroll
    for (int ct = 0; ct < 2; ++ct) {
      const int n = (g << 9) + jc0 + (ct << 4) + l15;
      #pragma unroll
      for (int t = 0; t < 8; ++t) {
        const int k = ((wv << 3) + t) * 32 + (lq << 3);
        Bg[g][ct][t] = *(const f16x8*)(wtg + (size_t)n * 1024 + k);
      }
    }
  f16x8 Bd[2][4];
  #pragma unroll
  for (int ct = 0; ct < 2; ++ct) {
    const int n = jc0 + (ct << 4) + l15;
    #pragma unroll
    for (int t = 0; t < 4; ++t) {
      const int k = ((wv << 2) + t) * 32 + (lq << 3);
      Bd[ct][t] = *(const f16x8*)(wtd + (size_t)n * 512 + k);
    }
  }

  // ---- biases -> LDS once ----
  if (tid < 160) {
    const int u = tid >> 4, c = tid & 15;
    const float* bp = (u < 2) ? bi : (u < 4) ? bf : (u < 6) ? bog : (u < 8) ? bc : bdec;
    biasS[u][c] = bp[jc0 + ((u & 1) << 4) + c];
  }
  __syncthreads();

  const f16* AgF = &Ag[0][0];
  const f16* AdF = &Ad[0][0];
  const int a_base  = l15 * 1032 + (lq << 3);
  const int ad_base = l15 * 520 + (lq << 3);

  // owner-stationary c state: thread owns (row er, cols 2*eq, 2*eq+1)
  const int er   = tid >> 4;
  const int eq   = tid & 15;
  const int gb_e = row0 + er;
  float c_reg[2] = {0.f, 0.f};

  int* const my_bar = &bar[rowg * 64];
  const int gb0 = row0 + (wv << 2);    // first of this wave's 4 staged rows

  for (int s = 0; s < S_; ++s) {
    const int cur = s & 1, nxt = cur ^ 1;
    const f16* hcur = h16 + (size_t)cur * (B_ * H_);
    const f16* ccur = c16 + (size_t)cur * (B_ * H_);

    // ---- arrive ASAP (prev step's stores drained by prev syncthreads) ----
    if (s > 0 && tid == 0)
      __hip_atomic_fetch_add(my_bar, 1, __ATOMIC_RELAXED, __HIP_MEMORY_SCOPE_AGENT);

    // ---- overlap window: x stage + bias init while peers arrive ----
    #pragma unroll
    for (int rr = 0; rr < 4; ++rr) {
      const int r = (wv << 2) + rr;
      const int gb = row0 + r;
      const float4* xr = (const float4*)(x + ((size_t)gb * S_ + s) * D_);
      float4 v0 = xr[lane * 2];
      float4 v1 = xr[lane * 2 + 1];
      f16x8 xv;
      xv[0] = (f16)v0.x; xv[1] = (f16)v0.y; xv[2] = (f16)v0.z; xv[3] = (f16)v0.w;
      xv[4] = (f16)v1.x; xv[5] = (f16)v1.y; xv[6] = (f16)v1.z; xv[7] = (f16)v1.w;
      *(f16x8*)&Ag[r][lane << 3] = xv;
    }
    {
      const int r = tid >> 4, c = tid & 15;
      const int li = r * 17 + c;
      #pragma unroll
      for (int u = 0; u < 10; ++u) accS[u][li] = biasS[u][c];
    }

    // ---- wait for row-group peers (h/c of step s-1 published) ----
    if (s > 0 && tid == 0) {
      while (__hip_atomic_load(my_bar, __ATOMIC_RELAXED, __HIP_MEMORY_SCOPE_AGENT)
             < 16 * s)
        __builtin_amdgcn_s_sleep(1);
    }
    __syncthreads();

    // ---- h/c staging: ONE asm block, 8 pipelined sc1 b128 loads, 1 drain ----
    {
      const f16* hp = hcur + (size_t)gb0 * H_ + (lane << 3);
      const f16* cp = ccur + (size_t)gb0 * H_ + (lane << 3);
      u32x4 h0, h1, h2, h3, c0, c1, c2, c3;
      asm volatile(
        "global_load_dwordx4 %0, %8, off sc1\n\t"
        "global_load_dwordx4 %1, %8, off offset:1024 sc1\n\t"
        "global_load_dwordx4 %2, %8, off offset:2048 sc1\n\t"
        "global_load_dwordx4 %3, %8, off offset:3072 sc1\n\t"
        "global_load_dwordx4 %4, %9, off sc1\n\t"
        "global_load_dwordx4 %5, %9, off offset:1024 sc1\n\t"
        "global_load_dwordx4 %6, %9, off offset:2048 sc1\n\t"
        "global_load_dwordx4 %7, %9, off offset:3072 sc1\n\t"
        "s_waitcnt vmcnt(0)"
        : "=&v"(h0), "=&v"(h1), "=&v"(h2), "=&v"(h3),
          "=&v"(c0), "=&v"(c1), "=&v"(c2), "=&v"(c3)
        : "v"(hp), "v"(cp)
        : "memory");
      const int r = wv << 2;
      *(u32x4*)&Ag[r + 0][512 + (lane << 3)] = h0;
      *(u32x4*)&Ag[r + 1][512 + (lane << 3)] = h1;
      *(u32x4*)&Ag[r + 2][512 + (lane << 3)] = h2;
      *(u32x4*)&Ag[r + 3][512 + (lane << 3)] = h3;
      *(u32x4*)&Ad[r + 0][lane << 3] = c0;
      *(u32x4*)&Ad[r + 1][lane << 3] = c1;
      *(u32x4*)&Ad[r + 2][lane << 3] = c2;
      *(u32x4*)&Ad[r + 3][lane << 3] = c3;
    }
    __syncthreads();

    // ---- MFMA: K split across 4 waves ----
    f32x4 acc[10];
    #pragma unroll
    for (int u = 0; u < 10; ++u) acc[u] = (f32x4){0.f, 0.f, 0.f, 0.f};
    #pragma unroll
    for (int t = 0; t < 8; ++t) {
      f16x8 a = *(const f16x8*)(AgF + a_base + ((wv << 3) + t) * 32);
      #pragma unroll
      for (int g = 0; g < 4; ++g)
        #pragma unroll
        for (int ct = 0; ct < 2; ++ct)
          acc[(g << 1) + ct] =
              __builtin_amdgcn_mfma_f32_16x16x32_f16(a, Bg[g][ct][t], acc[(g << 1) + ct], 0, 0, 0);
    }
    #pragma unroll
    for (int t = 0; t < 4; ++t) {
      f16x8 a = *(const f16x8*)(AdF + ad_base + ((wv << 2) + t) * 32);
      acc[8] = __builtin_amdgcn_mfma_f32_16x16x32_f16(a, Bd[0][t], acc[8], 0, 0, 0);
      acc[9] = __builtin_amdgcn_mfma_f32_16x16x32_f16(a, Bd[1][t], acc[9], 0, 0, 0);
    }
    // reduce wave partials; C-frag: row=(lane>>4)*4+i, col=lane&15
    #pragma unroll
    for (int u = 0; u < 10; ++u)
      #pragma unroll
      for (int i = 0; i < 4; ++i)
        atomicAdd(&accS[u][((lq << 2) + i) * 17 + l15], acc[u][i]);
    __syncthreads();

    // ---- elementwise cell update: thread owns (er, 2*eq) and (er, 2*eq+1) ----
    {
      const float tv = tim[(size_t)gb_e * S_ + s];
      const float T  = 1.0f / __logf(tv + 2.7183f);   // exact ref constant
      float hv[2];
      #pragma unroll
      for (int j = 0; j < 2; ++j) {
        const int cc = (eq << 1) + j;
        const int ct = cc >> 4, cl = cc & 15;
        const int li = er * 17 + cl;
        const float pi = accS[0 + ct][li];
        const float pf = accS[2 + ct][li];
        const float po = accS[4 + ct][li];
        const float pc = accS[6 + ct][li];
        const float ps = accS[8 + ct][li];
        const float cst  = fast_tanh(ps);
        const float chat = c_reg[j] - cst + T * cst;
        const float cnew = fast_sigmoid(pf) * chat + fast_sigmoid(pi) * fast_tanh(pc);
        const float hnew = fast_sigmoid(po) * fast_tanh(cnew);
        c_reg[j] = cnew;
        hv[j] = hnew;
      }
      const size_t off = (size_t)gb_e * H_ + jc0 + (eq << 1);
      st_agent((unsigned*)(h16 + (size_t)nxt * (B_ * H_) + off), pack_f16x2(hv[0], hv[1]));
      st_agent((unsigned*)(c16 + (size_t)nxt * (B_ * H_) + off), pack_f16x2(c_reg[0], c_reg[1]));
      if (s == S_ - 1) {
        *(float2*)(hf32 + off) = make_float2(hv[0], hv[1]);
      }
    }
    __syncthreads();   // drains all waves' sc1 stores before next arrive
  }
}

// ---------------------------------------------------------------------------
// Head: out = relu(h_last @ Wo + bo) @ W_softmax + b_softmax   (fp32 exact)
// ---------------------------------------------------------------------------
__global__ void head_kernel(const float* __restrict__ hf32,
                            const float* __restrict__ Wo, const float* __restrict__ bo,
                            const float* __restrict__ Wsm, const float* __restrict__ bsm,
                            float* __restrict__ out)
{
  __shared__ float fcS[4][64];
  const int tid = threadIdx.x;
  const int r = tid >> 6, j = tid & 63;
  const int b = blockIdx.x * 4 + r;
  const float* h = hf32 + (size_t)b * 512;
  float acc = 0.f;
  #pragma unroll 8
  for (int k = 0; k < 512; ++k) acc += h[k] * Wo[k * 64 + j];
  fcS[r][j] = fmaxf(acc + bo[j], 0.f);
  __syncthreads();
  if (tid < 8) {
    const int rr = tid >> 1, o = tid & 1;
    float s = bsm[o];
    #pragma unroll 8
    for (int jj = 0; jj < 64; ++jj) s += fcS[rr][jj] * Wsm[jj * 2 + o];
    out[(size_t)(blockIdx.x * 4 + rr) * 2 + o] = s;
  }
}

// ---------------------------------------------------------------------------
extern "C" void kernel_launch(void* const* d_in, const int* in_sizes, int n_in,
                              void* d_out, int out_size, void* d_ws, size_t ws_size,
                              hipStream_t stream)
{
  if (ws_size < (size_t)WS_END) return;

  const float* x    = (const float*)d_in[0];
  const float* tim  = (const float*)d_in[1];
  const float* Wi   = (const float*)d_in[2];
  const float* Ui   = (const float*)d_in[3];
  const float* bi   = (const float*)d_in[4];
  const float* Wf   = (const float*)d_in[5];
  const float* Uf   = (const float*)d_in[6];
  const float* bf   = (const float*)d_in[7];
  const float* Wog  = (const float*)d_in[8];
  const float* Uog  = (const float*)d_in[9];
  const float* bog  = (const float*)d_in[10];
  const float* Wc   = (const float*)d_in[11];
  const float* Uc   = (const float*)d_in[12];
  const float* bc   = (const float*)d_in[13];
  const float* Wd   = (const float*)d_in[14];
  const float* bd   = (const float*)d_in[15];
  const float* Wo   = (const float*)d_in[16];
  const float* bo   = (const float*)d_in[17];
  const float* Wsm  = (const float*)d_in[18];
  const float* bsm  = (const float*)d_in[19];

  char* ws    = (char*)d_ws;
  f16*  wtg   = (f16*)(ws + WS_WTG);
  f16*  wtd   = (f16*)(ws + WS_WTD);
  f16*  h16   = (f16*)(ws + WS_H16);
  f16*  c16   = (f16*)(ws + WS_C16);
  float* hf32 = (float*)(ws + WS_HF32);
  int*  bar   = (int*)(ws + WS_BAR);

  // zero h/c buffers + hf32 + barrier (ws is poisoned 0xAA before each call)
  (void)hipMemsetAsync(ws + WS_H16, 0, WS_END - WS_H16, stream);

  pack_weights<<<9216, 256, 0, stream>>>(Wi, Ui, Wf, Uf, Wog, Uog, Wc, Uc, Wd, wtg, wtd);
  tlstm_main<<<256, 256, 0, stream>>>(x, tim, bi, bf, bog, bc, bd, wtg, wtd,
                                      h16, c16, hf32, bar);
  head_kernel<<<64, 256, 0, stream>>>(hf32, Wo, bo, Wsm, bsm, (float*)d_out);
}

// Round 4
// 8606.611 us; speedup vs baseline: 2.4557x; 1.0835x over previous
//
#include <hip/hip_runtime.h>

// ---------------------------------------------------------------------------
// TLSTM (time-aware LSTM): B=256, S=512, D=H=512, FC=64, O=2
//
// Round-4 design: fully XCD-local communication (L2-only, zero IC ops).
//   * persistent kernel, 256 WGs = 16 rowg x 16 colg; all WGs of a rowg land
//     on one XCD (bid&7 == rowg&7) -> h/c exchange + barrier via shared L2.
//   * CDNA L1 is read-only: plain stores go straight to L2 (write-back, no
//     HBM write-through). Peer reads use sc0 loads (L1 bypass, L2 serve).
//   * barrier: 16-slot epoch flag array per rowg; each WG plain-stores its
//     epoch, wave0 lanes 0-15 poll all slots in parallel (ballot). No atomic
//     RMW -> no fabric serialization, no Infinity-Cache round trips.
//   * x_t and tim prefetched one step ahead into registers (HBM latency off
//     the serial chain).
//   * weights f16 B^T fragments register/AGPR-resident (unchanged).
// ---------------------------------------------------------------------------

typedef _Float16 f16;
typedef _Float16 f16x8 __attribute__((ext_vector_type(8)));
typedef float f32x4 __attribute__((ext_vector_type(4)));
typedef unsigned u32x4 __attribute__((ext_vector_type(4)));

#define B_ 256
#define S_ 512
#define D_ 512
#define H_ 512

// workspace layout (bytes)
#define WS_WTG  0u          // f16 [2048][1024] gate weights^T (W|U stacked on K)
#define WS_WTD  4194304u    // f16 [512][512]   decomp weights^T
#define WS_H16  4718592u    // f16 [2][256][512] h double buffer
#define WS_C16  5242880u    // f16 [2][256][512] c double buffer
#define WS_HF32 5767168u    // f32 [256][512]   h last (for head)
#define WS_FLG  6291456u    // u32 [16][16] epoch flags (rowg-major, 64B/rowg)
#define WS_END  6292480u

__device__ __forceinline__ float fast_sigmoid(float x) {
  return 1.0f / (1.0f + __expf(-x));
}
__device__ __forceinline__ float fast_tanh(float x) {
  x = fminf(15.0f, fmaxf(-15.0f, x));
  float e = __expf(2.0f * x);
  return (e - 1.0f) / (e + 1.0f);
}
__device__ __forceinline__ unsigned pack_f16x2(float a, float b) {
  union { f16 h[2]; unsigned u; } p;
  p.h[0] = (f16)a; p.h[1] = (f16)b;
  return p.u;
}

// ---------------------------------------------------------------------------
// Pack weights: WT_g[n][k] (n = gate*512+col; k<512 -> W[k][col], k>=512 ->
// U[k-512][col]), WT_d[n][k] = W_decomp[k][n].
// ---------------------------------------------------------------------------
__global__ void pack_weights(const float* __restrict__ Wi, const float* __restrict__ Ui,
                             const float* __restrict__ Wf, const float* __restrict__ Uf,
                             const float* __restrict__ Wog, const float* __restrict__ Uog,
                             const float* __restrict__ Wc, const float* __restrict__ Uc,
                             const float* __restrict__ Wd,
                             f16* __restrict__ wtg, f16* __restrict__ wtd)
{
  const int idx = blockIdx.x * 256 + threadIdx.x;
  if (idx < 2048 * 1024) {
    const int n = idx >> 10, k = idx & 1023;
    const int g = n >> 9, j = n & 511;
    const float* W[8] = {Wi, Ui, Wf, Uf, Wog, Uog, Wc, Uc};
    const float* src = W[(g << 1) + (k >> 9)];
    wtg[idx] = (f16)src[(size_t)(k & 511) * 512 + j];
  } else {
    const int i2 = idx - 2048 * 1024;
    const int n = i2 >> 9, k = i2 & 511;
    wtd[i2] = (f16)Wd[(size_t)k * 512 + n];
  }
}

// ---------------------------------------------------------------------------
// Main persistent kernel.
// ---------------------------------------------------------------------------
__global__ void __launch_bounds__(256, 1)
tlstm_main(const float* __restrict__ x, const float* __restrict__ tim,
           const float* __restrict__ bi, const float* __restrict__ bf,
           const float* __restrict__ bog, const float* __restrict__ bc,
           const float* __restrict__ bdec,
           const f16* __restrict__ wtg, const f16* __restrict__ wtd,
           f16* __restrict__ h16, f16* __restrict__ c16,
           float* __restrict__ hf32, unsigned* __restrict__ flg_base)
{
  __shared__ __align__(16) f16 Ag[16][1032];   // [row][k]: k<512 x_t, k>=512 h_prev
  __shared__ __align__(16) f16 Ad[16][520];    // [row][k]: c_prev
  __shared__ float accS[10][272];              // 10 16x16 tiles, row stride 17
  __shared__ float biasS[10][16];

  const int tid  = threadIdx.x;
  const int lane = tid & 63;
  const int wv   = tid >> 6;     // wave 0..3
  const int l15  = lane & 15;
  const int lq   = lane >> 4;
  const int bid  = blockIdx.x;
  const int rowg = bid & 15;     // all 16 colg WGs of a rowg share one XCD
  const int colg = bid >> 4;
  const int row0 = rowg << 4;    // 16 batch rows
  const int jc0  = colg << 5;    // 32 h-columns

  // ---- persistent weight B-fragments in registers/AGPRs ----
  f16x8 Bg[4][2][8];
  #pragma unroll
  for (int g = 0; g < 4; ++g)
    #pragma unroll
    for (int ct = 0; ct < 2; ++ct) {
      const int n = (g << 9) + jc0 + (ct << 4) + l15;
      #pragma unroll
      for (int t = 0; t < 8; ++t) {
        const int k = ((wv << 3) + t) * 32 + (lq << 3);
        Bg[g][ct][t] = *(const f16x8*)(wtg + (size_t)n * 1024 + k);
      }
    }
  f16x8 Bd[2][4];
  #pragma unroll
  for (int ct = 0; ct < 2; ++ct) {
    const int n = jc0 + (ct << 4) + l15;
    #pragma unroll
    for (int t = 0; t < 4; ++t) {
      const int k = ((wv << 2) + t) * 32 + (lq << 3);
      Bd[ct][t] = *(const f16x8*)(wtd + (size_t)n * 512 + k);
    }
  }

  // ---- biases -> LDS once ----
  if (tid < 160) {
    const int u = tid >> 4, c = tid & 15;
    const float* bp = (u < 2) ? bi : (u < 4) ? bf : (u < 6) ? bog : (u < 8) ? bc : bdec;
    biasS[u][c] = bp[jc0 + ((u & 1) << 4) + c];
  }
  __syncthreads();

  const f16* AgF = &Ag[0][0];
  const f16* AdF = &Ad[0][0];
  const int a_base  = l15 * 1032 + (lq << 3);
  const int ad_base = l15 * 520 + (lq << 3);

  // owner-stationary c state: thread owns (row er, cols 2*eq, 2*eq+1)
  const int er   = tid >> 4;
  const int eq   = tid & 15;
  const int gb_e = row0 + er;
  float c_reg[2] = {0.f, 0.f};

  unsigned* const flg = flg_base + rowg * 16;   // 64B line per rowg
  const int gb0 = row0 + (wv << 2);             // first of this wave's 4 rows

  // ---- preload x(s=0) + tim(s=0) into registers ----
  float4 px0[4], px1[4];
  float t_pf;
  #pragma unroll
  for (int rr = 0; rr < 4; ++rr) {
    const int gb = row0 + (wv << 2) + rr;
    const float4* xr = (const float4*)(x + ((size_t)gb * S_) * D_);
    px0[rr] = xr[lane * 2];
    px1[rr] = xr[lane * 2 + 1];
  }
  t_pf = tim[(size_t)gb_e * S_];

  for (int s = 0; s < S_; ++s) {
    const int cur = s & 1, nxt = cur ^ 1;
    const f16* hcur = h16 + (size_t)cur * (B_ * H_);
    const f16* ccur = c16 + (size_t)cur * (B_ * H_);

    // ---- write prefetched x_s to LDS (cvt fp32->f16) ----
    #pragma unroll
    for (int rr = 0; rr < 4; ++rr) {
      const int r = (wv << 2) + rr;
      f16x8 xv;
      xv[0] = (f16)px0[rr].x; xv[1] = (f16)px0[rr].y;
      xv[2] = (f16)px0[rr].z; xv[3] = (f16)px0[rr].w;
      xv[4] = (f16)px1[rr].x; xv[5] = (f16)px1[rr].y;
      xv[6] = (f16)px1[rr].z; xv[7] = (f16)px1[rr].w;
      *(f16x8*)&Ag[r][lane << 3] = xv;
    }
    // bias-init accumulator tiles
    {
      const int r = tid >> 4, c = tid & 15;
      const int li = r * 17 + c;
      #pragma unroll
      for (int u = 0; u < 10; ++u) accS[u][li] = biasS[u][c];
    }
    const float t_cur = t_pf;

    // ---- prefetch x(s+1) + tim(s+1): whole step to complete ----
    if (s + 1 < S_) {
      #pragma unroll
      for (int rr = 0; rr < 4; ++rr) {
        const int gb = row0 + (wv << 2) + rr;
        const float4* xr = (const float4*)(x + ((size_t)gb * S_ + (s + 1)) * D_);
        px0[rr] = xr[lane * 2];
        px1[rr] = xr[lane * 2 + 1];
      }
      t_pf = tim[(size_t)gb_e * S_ + s + 1];
    }

    // ---- wait for row-group peers: poll 16 epoch flags in parallel ----
    if (s > 0 && wv == 0) {
      const unsigned* fp = flg + l15;
      const unsigned tgt = (unsigned)s;
      while (true) {
        unsigned v;
        asm volatile("global_load_dword %0, %1, off sc0\n\t"
                     "s_waitcnt vmcnt(0)"
                     : "=v"(v) : "v"(fp) : "memory");
        unsigned long long m = __ballot(v >= tgt);
        if ((m & 0xFFFFull) == 0xFFFFull) break;
        __builtin_amdgcn_s_sleep(1);
      }
    }
    __syncthreads();

    // ---- h/c staging: sc0 loads (L1 bypass, L2-served), batched ----
    {
      const f16* hp = hcur + (size_t)gb0 * H_ + (lane << 3);
      const f16* cp = ccur + (size_t)gb0 * H_ + (lane << 3);
      u32x4 h0, h1, h2, h3;
      asm volatile(
        "global_load_dwordx4 %0, %4, off sc0\n\t"
        "global_load_dwordx4 %1, %4, off offset:1024 sc0\n\t"
        "global_load_dwordx4 %2, %4, off offset:2048 sc0\n\t"
        "global_load_dwordx4 %3, %4, off offset:3072 sc0\n\t"
        "s_waitcnt vmcnt(0)"
        : "=&v"(h0), "=&v"(h1), "=&v"(h2), "=&v"(h3)
        : "v"(hp) : "memory");
      const int r = wv << 2;
      *(u32x4*)&Ag[r + 0][512 + (lane << 3)] = h0;
      *(u32x4*)&Ag[r + 1][512 + (lane << 3)] = h1;
      *(u32x4*)&Ag[r + 2][512 + (lane << 3)] = h2;
      *(u32x4*)&Ag[r + 3][512 + (lane << 3)] = h3;
      u32x4 c0, c1, c2, c3;
      asm volatile(
        "global_load_dwordx4 %0, %4, off sc0\n\t"
        "global_load_dwordx4 %1, %4, off offset:1024 sc0\n\t"
        "global_load_dwordx4 %2, %4, off offset:2048 sc0\n\t"
        "global_load_dwordx4 %3, %4, off offset:3072 sc0\n\t"
        "s_waitcnt vmcnt(0)"
        : "=&v"(c0), "=&v"(c1), "=&v"(c2), "=&v"(c3)
        : "v"(cp) : "memory");
      *(u32x4*)&Ad[r + 0][lane << 3] = c0;
      *(u32x4*)&Ad[r + 1][lane << 3] = c1;
      *(u32x4*)&Ad[r + 2][lane << 3] = c2;
      *(u32x4*)&Ad[r + 3][lane << 3] = c3;
    }
    __syncthreads();

    // ---- MFMA: K split across 4 waves ----
    f32x4 acc[10];
    #pragma unroll
    for (int u = 0; u < 10; ++u) acc[u] = (f32x4){0.f, 0.f, 0.f, 0.f};
    #pragma unroll
    for (int t = 0; t < 8; ++t) {
      f16x8 a = *(const f16x8*)(AgF + a_base + ((wv << 3) + t) * 32);
      #pragma unroll
      for (int g = 0; g < 4; ++g)
        #pragma unroll
        for (int ct = 0; ct < 2; ++ct)
          acc[(g << 1) + ct] =
              __builtin_amdgcn_mfma_f32_16x16x32_f16(a, Bg[g][ct][t], acc[(g << 1) + ct], 0, 0, 0);
    }
    #pragma unroll
    for (int t = 0; t < 4; ++t) {
      f16x8 a = *(const f16x8*)(AdF + ad_base + ((wv << 2) + t) * 32);
      acc[8] = __builtin_amdgcn_mfma_f32_16x16x32_f16(a, Bd[0][t], acc[8], 0, 0, 0);
      acc[9] = __builtin_amdgcn_mfma_f32_16x16x32_f16(a, Bd[1][t], acc[9], 0, 0, 0);
    }
    // reduce wave partials; C-frag: row=(lane>>4)*4+i, col=lane&15
    #pragma unroll
    for (int u = 0; u < 10; ++u)
      #pragma unroll
      for (int i = 0; i < 4; ++i)
        atomicAdd(&accS[u][((lq << 2) + i) * 17 + l15], acc[u][i]);
    __syncthreads();

    // ---- elementwise cell update: thread owns (er, 2*eq) and (er, 2*eq+1) ----
    {
      const float T = 1.0f / __logf(t_cur + 2.7183f);   // exact ref constant
      float hv[2];
      #pragma unroll
      for (int j = 0; j < 2; ++j) {
        const int cc = (eq << 1) + j;
        const int ct = cc >> 4, cl = cc & 15;
        const int li = er * 17 + cl;
        const float pi = accS[0 + ct][li];
        const float pf = accS[2 + ct][li];
        const float po = accS[4 + ct][li];
        const float pc = accS[6 + ct][li];
        const float ps = accS[8 + ct][li];
        const float cst  = fast_tanh(ps);
        const float chat = c_reg[j] - cst + T * cst;
        const float cnew = fast_sigmoid(pf) * chat + fast_sigmoid(pi) * fast_tanh(pc);
        const float hnew = fast_sigmoid(po) * fast_tanh(cnew);
        c_reg[j] = cnew;
        hv[j] = hnew;
      }
      // plain stores: land in this XCD's L2 (CDNA L1 is read-only)
      const size_t off = (size_t)gb_e * H_ + jc0 + (eq << 1);
      *(unsigned*)(h16 + (size_t)nxt * (B_ * H_) + off) = pack_f16x2(hv[0], hv[1]);
      *(unsigned*)(c16 + (size_t)nxt * (B_ * H_) + off) = pack_f16x2(c_reg[0], c_reg[1]);
      if (s == S_ - 1) {
        *(float2*)(hf32 + off) = make_float2(hv[0], hv[1]);
      }
    }
    __syncthreads();   // compiler emits s_waitcnt vmcnt(0) before s_barrier:
                       // all waves' h/c stores are in L2 here

    // ---- publish epoch: plain store to our own flag slot ----
    if (tid == 0) {
      unsigned* sp = flg + colg;
      unsigned val = (unsigned)(s + 1);
      asm volatile("global_store_dword %0, %1, off" :: "v"(sp), "v"(val) : "memory");
    }
  }
}

// ---------------------------------------------------------------------------
// Head: out = relu(h_last @ Wo + bo) @ W_softmax + b_softmax   (fp32 exact)
// ---------------------------------------------------------------------------
__global__ void head_kernel(const float* __restrict__ hf32,
                            const float* __restrict__ Wo, const float* __restrict__ bo,
                            const float* __restrict__ Wsm, const float* __restrict__ bsm,
                            float* __restrict__ out)
{
  __shared__ float fcS[4][64];
  const int tid = threadIdx.x;
  const int r = tid >> 6, j = tid & 63;
  const int b = blockIdx.x * 4 + r;
  const float* h = hf32 + (size_t)b * 512;
  float acc = 0.f;
  #pragma unroll 8
  for (int k = 0; k < 512; ++k) acc += h[k] * Wo[k * 64 + j];
  fcS[r][j] = fmaxf(acc + bo[j], 0.f);
  __syncthreads();
  if (tid < 8) {
    const int rr = tid >> 1, o = tid & 1;
    float s = bsm[o];
    #pragma unroll 8
    for (int jj = 0; jj < 64; ++jj) s += fcS[rr][jj] * Wsm[jj * 2 + o];
    out[(size_t)(blockIdx.x * 4 + rr) * 2 + o] = s;
  }
}

// ---------------------------------------------------------------------------
extern "C" void kernel_launch(void* const* d_in, const int* in_sizes, int n_in,
                              void* d_out, int out_size, void* d_ws, size_t ws_size,
                              hipStream_t stream)
{
  if (ws_size < (size_t)WS_END) return;

  const float* x    = (const float*)d_in[0];
  const float* tim  = (const float*)d_in[1];
  const float* Wi   = (const float*)d_in[2];
  const float* Ui   = (const float*)d_in[3];
  const float* bi   = (const float*)d_in[4];
  const float* Wf   = (const float*)d_in[5];
  const float* Uf   = (const float*)d_in[6];
  const float* bf   = (const float*)d_in[7];
  const float* Wog  = (const float*)d_in[8];
  const float* Uog  = (const float*)d_in[9];
  const float* bog  = (const float*)d_in[10];
  const float* Wc   = (const float*)d_in[11];
  const float* Uc   = (const float*)d_in[12];
  const float* bc   = (const float*)d_in[13];
  const float* Wd   = (const float*)d_in[14];
  const float* bd   = (const float*)d_in[15];
  const float* Wo   = (const float*)d_in[16];
  const float* bo   = (const float*)d_in[17];
  const float* Wsm  = (const float*)d_in[18];
  const float* bsm  = (const float*)d_in[19];

  char* ws    = (char*)d_ws;
  f16*  wtg   = (f16*)(ws + WS_WTG);
  f16*  wtd   = (f16*)(ws + WS_WTD);
  f16*  h16   = (f16*)(ws + WS_H16);
  f16*  c16   = (f16*)(ws + WS_C16);
  float* hf32 = (float*)(ws + WS_HF32);
  unsigned* flg = (unsigned*)(ws + WS_FLG);

  // zero h/c buffers + hf32 + flags (ws is poisoned 0xAA before each call)
  (void)hipMemsetAsync(ws + WS_H16, 0, WS_END - WS_H16, stream);

  pack_weights<<<9216, 256, 0, stream>>>(Wi, Ui, Wf, Uf, Wog, Uog, Wc, Uc, Wd, wtg, wtd);
  tlstm_main<<<256, 256, 0, stream>>>(x, tim, bi, bf, bog, bc, bd, wtg, wtd,
                                      h16, c16, hf32, flg);
  head_kernel<<<64, 256, 0, stream>>>(hf32, Wo, bo, Wsm, bsm, (float*)d_out);
}